// Round 5
// baseline (116.560 us; speedup 1.0000x reference)
//
#include <hip/hip_runtime.h>
#include <math.h>

// Biquad highpass IIR over [B=128, C=2, T=65536] f32.
// R5: R4's async-DMA structure with L_CHUNK=128 (read amplification 1.5x,
// down from R4's 2.0x). Each single-wave block owns 64 chunks of 128
// samples (+W=64 zero-state warm-up; R1 proved this exact geometry:
// absmax 0.0156 = f32 contraction noise). 6 tiles of 32 samples stream
// through 4 x 8KiB LDS buffers via global_load_lds_dwordx4 with a
// hand-placed vmcnt ladder (24/24/24/16/8/0) -- 32 KiB in flight per wave
// at the prologue. DMA lane->LDS layout is fixed (base + lane*16), so we
// permute WHICH global float4 each lane fetches (slot q holds row q>>3's
// float4 ((q&7)-row)&7) making compute-phase row reads conflict-free
// ds_read_b128 with zero copy phases. Outputs are written in-place into
// consumed staging buffers; ONE final store phase writes each chunk's
// full 512B contiguously (every instruction = 1 KiB linear, all sectors
// complete; no DMA after stores => vmcnt never waits on stores).

#define T_LEN    65536
#define L_CHUNK  128
#define W_WARM   64
#define TS       32
#define BLK      64                  // one wave per block
#define ROWS     64                  // chunks per wave
#define BUF_F    (ROWS * TS)         // 2048 floats = 8 KiB per buffer
#define BLOCKS_PER_CH 8              // (T_LEN/L_CHUNK)/ROWS

#define WAITVM(n) asm volatile("s_waitcnt vmcnt(" #n ")" ::: "memory")

__device__ __forceinline__ void lds_fence() {
    // orders DS ops (in-order per wave; block = one wave) without draining vmcnt
    asm volatile("s_waitcnt lgkmcnt(0)" ::: "memory");
}

// DMA one 8 KiB tile (64 rows x 32 floats) into LDS. Instr i writes lane k's
// 16B to buf + i*1024B + k*16B. Global source permuted: LDS float4 slot
// q = i*64+lane holds row l=q>>3's float4 #((q&7)-l)&7. Per-lane base bsf
// already folds in row l0=lane>>3 and j0=((lane&7)-l0)&7; instr i advances
// 8 rows = 8*L_CHUNK floats.
__device__ __forceinline__ void dma_tile(const float* __restrict__ x,
                                         int bsf, int tile, float* buf)
{
    #pragma unroll
    for (int i = 0; i < 8; ++i) {
        int pos = bsf + i * (8 * L_CHUNK) + tile * TS;
        pos = pos < 0 ? 0 : pos;     // block-0 pre-array clamp (values zeroed later)
        __builtin_amdgcn_global_load_lds(
            (__attribute__((address_space(1))) void*)(void*)(x + pos),
            (__attribute__((address_space(3))) void*)(buf + i * 256),
            16, 0, 0);
    }
}

template <bool WARM>
__device__ __forceinline__ void tile_filter(float* buf, int lane, bool ch0,
    float c_b0, float c_b1, float c_b2, float c_a1, float c_a2,
    float& x1, float& x2, float& y1, float& y2)
{
    float4 r[8];
    #pragma unroll
    for (int g = 0; g < 8; ++g)
        r[g] = *(float4*)&buf[(lane * 8 + ((g + lane) & 7)) * 4];

    if (WARM && ch0) {   // channel-start row: pre-channel warm reads are garbage => state 0
        #pragma unroll
        for (int g = 0; g < 8; ++g) r[g] = make_float4(0.f, 0.f, 0.f, 0.f);
    }

    #pragma unroll
    for (int g = 0; g < 8; ++g) {
        float4 v = r[g];
        float yv;
        yv = c_b0*v.x + c_b1*x1 + c_b2*x2 - c_a1*y1 - c_a2*y2;
        x2 = x1; x1 = v.x; y2 = y1; y1 = yv; v.x = yv;
        yv = c_b0*v.y + c_b1*x1 + c_b2*x2 - c_a1*y1 - c_a2*y2;
        x2 = x1; x1 = v.y; y2 = y1; y1 = yv; v.y = yv;
        yv = c_b0*v.z + c_b1*x1 + c_b2*x2 - c_a1*y1 - c_a2*y2;
        x2 = x1; x1 = v.z; y2 = y1; y1 = yv; v.z = yv;
        yv = c_b0*v.w + c_b1*x1 + c_b2*x2 - c_a1*y1 - c_a2*y2;
        x2 = x1; x1 = v.w; y2 = y1; y1 = yv; v.w = yv;
        if (!WARM) r[g] = v;
    }

    if (!WARM) {         // in-place: staging buffer becomes output buffer
        #pragma unroll
        for (int g = 0; g < 8; ++g)
            *(float4*)&buf[(lane * 8 + ((g + lane) & 7)) * 4] = r[g];
    }
}

__global__ __launch_bounds__(BLK, 4)
void hp_biquad_kernel(const float* __restrict__ x, float* __restrict__ y,
                      float c_b0, float c_b1, float c_b2, float c_a1, float c_a2)
{
    __shared__ float lds4[4 * BUF_F];           // 32 KiB => 5 blocks/CU
    const int lane = threadIdx.x;
    const int cg0  = blockIdx.x * ROWS;
    const bool ch0 = ((blockIdx.x & (BLOCKS_PER_CH - 1)) == 0) && (lane == 0);

    // per-lane DMA source base (floats)
    const int l0  = lane >> 3;
    const int j0  = ((lane & 7) - l0) & 7;
    const int bsf = (cg0 + l0) * L_CHUNK - W_WARM + j0 * 4;

    float* A = lds4;                 // tile t -> buffer (t & 3)
    float* B = lds4 + BUF_F;
    float* C = lds4 + 2 * BUF_F;
    float* D = lds4 + 3 * BUF_F;

    float x1 = 0.f, x2 = 0.f, y1 = 0.f, y2 = 0.f;

    // ---- deep prologue: 4 tiles (32 KiB) in flight ----
    dma_tile(x, bsf, 0, A);                    // out: 8
    dma_tile(x, bsf, 1, B);                    // out: 16
    dma_tile(x, bsf, 2, C);                    // out: 24
    dma_tile(x, bsf, 3, D);                    // out: 32

    WAITVM(24);                                 // t0 landed
    tile_filter<true>(A, lane, ch0, c_b0, c_b1, c_b2, c_a1, c_a2, x1, x2, y1, y2);
    lds_fence();                                // A's reads retired before refill
    dma_tile(x, bsf, 4, A);                    // out: <=24(t1..t3) + 8

    WAITVM(24);                                 // t1 landed
    tile_filter<true>(B, lane, ch0, c_b0, c_b1, c_b2, c_a1, c_a2, x1, x2, y1, y2);
    lds_fence();
    dma_tile(x, bsf, 5, B);                    // out: <=24(t2..t4) + 8

    WAITVM(24);                                 // t2 landed
    tile_filter<false>(C, lane, ch0, c_b0, c_b1, c_b2, c_a1, c_a2, x1, x2, y1, y2);
    WAITVM(16);                                 // t3 landed
    tile_filter<false>(D, lane, ch0, c_b0, c_b1, c_b2, c_a1, c_a2, x1, x2, y1, y2);
    WAITVM(8);                                  // t4 landed
    tile_filter<false>(A, lane, ch0, c_b0, c_b1, c_b2, c_a1, c_a2, x1, x2, y1, y2);
    WAITVM(0);                                  // t5 landed
    tile_filter<false>(B, lane, ch0, c_b0, c_b1, c_b2, c_a1, c_a2, x1, x2, y1, y2);
    lds_fence();                                // in-place writes ordered before store reads

    // ---- combined store: data tiles t2..t5 live in C,D,A,B.
    // f4 index q = lane + p*64; chunk seg = q>>5, within-chunk float4
    // jj = q&31 -> tile jj>>3 -> buffer ((jj>>3)+2)&3. Each instruction
    // writes 1 KiB perfectly linear; each chunk's 512B written whole. ----
    const int ybase = cg0 * L_CHUNK + lane * 4;
    #pragma unroll
    for (int p = 0; p < 32; ++p) {
        int q   = lane + p * 64;
        int seg = q >> 5;
        int jj  = q & 31;
        int g   = jj & 7;
        const float* bb = lds4 + (((jj >> 3) + 2) & 3) * BUF_F;
        float4 v = *(const float4*)&bb[(seg * 8 + ((g + seg) & 7)) * 4];
        *(float4*)(y + ybase + p * 256) = v;
    }
}

extern "C" void kernel_launch(void* const* d_in, const int* in_sizes, int n_in,
                              void* d_out, int out_size, void* d_ws, size_t ws_size,
                              hipStream_t stream)
{
    const float* x = (const float*)d_in[0];
    float* y = (float*)d_out;

    // Same double-precision coefficient math as the reference, cast to f32.
    const double SR = 16000.0, FLO = 200.0, FHI = 1200.0;
    const double freq   = 0.5 * (FLO + FHI);      // 700 Hz
    const double cutoff = freq / SR;
    const double q      = 0.70710678;
    const double w0 = 2.0 * M_PI * cutoff;
    const double cw = cos(w0), sw = sin(w0);
    const double alpha = sw / (2.0 * q);
    const double b0 = (1.0 + cw) / 2.0;
    const double b1 = -(1.0 + cw);
    const double b2 = (1.0 + cw) / 2.0;
    const double a0 = 1.0 + alpha;
    const double a1 = -2.0 * cw;
    const double a2 = 1.0 - alpha;
    const float fb0 = (float)(b0 / a0), fb1 = (float)(b1 / a0), fb2 = (float)(b2 / a0);
    const float fa1 = (float)(a1 / a0), fa2 = (float)(a2 / a0);

    const int total  = 128 * 2 * T_LEN;            // 16,777,216 samples
    const int chunks = total / L_CHUNK;            // 131,072
    const int blocks = chunks / ROWS;              // 2048 single-wave blocks

    hp_biquad_kernel<<<blocks, BLK, 0, stream>>>(x, y, fb0, fb1, fb2, fa1, fa2);
    (void)in_sizes; (void)n_in; (void)out_size; (void)d_ws; (void)ws_size;
}